// Round 2
// baseline (1113.565 us; speedup 1.0000x reference)
//
#include <hip/hip_runtime.h>

// ---------------------------------------------------------------------------
// GraphEncoder: B=32 graphs x N=128 nodes, E=128, H=8 heads, DH=16, L=4 layers
// M=16384 edges, ATOM=64, BOND=15, RBF K=32 -> EIN=47 (+1 virtual bias row)
// Round 0/1: fp32 correctness baseline. Edge network = fused on-the-fly GEMM.
// ---------------------------------------------------------------------------

__global__ __launch_bounds__(256) void k_zero(float* __restrict__ p, int n) {
  int i = blockIdx.x * 256 + threadIdx.x;
  if (i < n) p[i] = 0.0f;
}

// h[n,e] = x[n,:64] @ Wproj[:,e] + bproj[e]
__global__ __launch_bounds__(128) void k_node_proj(const float* __restrict__ x,
    const float* __restrict__ W, const float* __restrict__ b, float* __restrict__ h) {
  __shared__ float xs[64];
  int n = blockIdx.x, e = threadIdx.x;
  if (e < 64) xs[e] = x[n * 64 + e];
  __syncthreads();
  float acc = b[e];
#pragma unroll
  for (int a = 0; a < 64; a++) acc += xs[a] * W[a * 128 + e];
  h[n * 128 + e] = acc;
}

// ea2[m, 0:15] = ea[m,0:15]; ea2[m,15:47] = gaussian RBF(dist); ea2[m,47] = 1.0
__global__ __launch_bounds__(256) void k_rbf(const float* __restrict__ ea, float* __restrict__ ea2) {
  int idx = blockIdx.x * 256 + threadIdx.x;  // covers M*48
  int m = idx / 48, c = idx % 48;
  float v;
  if (c < 15) {
    v = ea[m * 16 + c];
  } else if (c < 47) {
    int i = c - 15;
    float d = fminf(10.0f, fmaxf(0.0f, ea[m * 16 + 15]));
    float ctr = 5.0f * (float)i / 31.0f;       // linspace(0, 5, 32)
    float diff = d - ctr;
    v = __expf(-38.44f * diff * diff);          // gamma = (31/5)^2 = 38.44 exact
  } else {
    v = 1.0f;                                   // virtual channel for blin
  }
  ea2[m * 48 + c] = v;
}

// Fused EdgeNetwork GEMM + scatter:
//   msg[m,e] = sum_{c<47} ea2[m,c] * sum_f Wlin[c, e*128+f] * h[src[m], f]
//            + sum_f blin[e*128+f] * h[src[m], f]          (c==47, coeff 1)
//   atomicAdd(agg[dst[m], e], msg[m,e])
// Tile: BM=64 edges x full E=128 cols. 256 threads, micro-tile 4m x 8e.
__global__ __launch_bounds__(256) void k_edge_gemm(const float* __restrict__ ea2,
    const int* __restrict__ ei, const float* __restrict__ h,
    const float* __restrict__ Wlin, const float* __restrict__ blin,
    float* __restrict__ agg) {
  __shared__ float hs[64][129];   // gathered source-node features (padded)
  __shared__ float et[64][48];    // ea2 tile
  __shared__ float wt[32][129];   // Wlin chunk, transposed to [f][e] (padded)
  __shared__ int srcs[64], dsts[64];

  int t = threadIdx.x;
  int m0 = blockIdx.x * 64;
  if (t < 64) { srcs[t] = ei[16384 + m0 + t]; dsts[t] = ei[m0 + t]; }
  __syncthreads();
#pragma unroll
  for (int i = 0; i < 32; i++) {            // 64*128 = 8192 elems
    int j = t + i * 256;
    int mi = j >> 7, f = j & 127;
    hs[mi][f] = h[srcs[mi] * 128 + f];
  }
#pragma unroll
  for (int i = 0; i < 12; i++) {            // 64*48 = 3072 elems
    int j = t + i * 256;
    int mi = j / 48, c = j % 48;
    et[mi][c] = ea2[(m0 + mi) * 48 + c];
  }

  int tm = t >> 4;   // 0..15 -> 4 edges each
  int te = t & 15;   // 0..15 -> e = k*16 + te (interleaved: conflict-free)
  float acc[4][8] = {};

  for (int c = 0; c < 48; c++) {
    const float* Wrow = (c < 47) ? (Wlin + c * 16384) : blin;
    float am[4];
    __syncthreads();   // protect et/hs on first iter, wt reuse on later iters
#pragma unroll
    for (int mi = 0; mi < 4; mi++) am[mi] = et[tm * 4 + mi][c];
    for (int fc = 0; fc < 4; fc++) {
      if (fc) __syncthreads();
#pragma unroll
      for (int i = 0; i < 16; i++) {        // stage 32f x 128e chunk
        int j = t + i * 256;
        int e = j >> 5, f = j & 31;
        wt[f][e] = Wrow[e * 128 + fc * 32 + f];
      }
      __syncthreads();
#pragma unroll 4
      for (int f = 0; f < 32; f++) {
        float wv[8];
#pragma unroll
        for (int k = 0; k < 8; k++) wv[k] = wt[f][k * 16 + te];
#pragma unroll
        for (int mi = 0; mi < 4; mi++) {
          float ah = am[mi] * hs[tm * 4 + mi][fc * 32 + f];
#pragma unroll
          for (int k = 0; k < 8; k++) acc[mi][k] += ah * wv[k];
        }
      }
    }
  }
#pragma unroll
  for (int mi = 0; mi < 4; mi++) {
    int dst = dsts[tm * 4 + mi];
#pragma unroll
    for (int k = 0; k < 8; k++)
      atomicAdd(&agg[dst * 128 + k * 16 + te], acc[mi][k]);
  }
}

// out[n,:] = LN(in[n,:] (+ res[n,:])) * g + b     (E=128, 128 threads)
__global__ __launch_bounds__(128) void k_ln(const float* __restrict__ in,
    const float* __restrict__ res, const float* __restrict__ g,
    const float* __restrict__ b, float* __restrict__ out) {
  int n = blockIdx.x, e = threadIdx.x;
  float v = in[n * 128 + e];
  if (res) v += res[n * 128 + e];
  float s = v, s2 = v * v;
#pragma unroll
  for (int o = 1; o < 64; o <<= 1) { s += __shfl_xor(s, o); s2 += __shfl_xor(s2, o); }
  __shared__ float r0[2], r1[2];
  int wid = e >> 6;
  if ((e & 63) == 0) { r0[wid] = s; r1[wid] = s2; }
  __syncthreads();
  float ts = r0[0] + r0[1], ts2 = r1[0] + r1[1];
  float mu = ts * (1.0f / 128.0f);
  float var = fmaxf(ts2 * (1.0f / 128.0f) - mu * mu, 0.0f);
  float inv = rsqrtf(var + 1e-5f);
  out[n * 128 + e] = (v - mu) * inv * g[e] + b[e];
}

// pairwise distances per graph: db[b,i,j]
__global__ __launch_bounds__(128) void k_dist(const float* __restrict__ pos, float* __restrict__ db) {
  int bi = blockIdx.x;           // b*128 + i
  int b = bi >> 7, i = bi & 127, j = threadIdx.x;
  float x0 = pos[(b * 128 + i) * 3 + 0];
  float y0 = pos[(b * 128 + i) * 3 + 1];
  float z0 = pos[(b * 128 + i) * 3 + 2];
  float dx = x0 - pos[(b * 128 + j) * 3 + 0];
  float dy = y0 - pos[(b * 128 + j) * 3 + 1];
  float dz = z0 - pos[(b * 128 + j) * 3 + 2];
  float d2 = dx * dx + dy * dy + dz * dz;
  db[b * 16384 + i * 128 + j] = (d2 > 0.0f) ? sqrtf(d2) : 0.0f;
}

// q/k/v = xp @ W* + b*   (16 nodes per block, 128 threads = one output col each)
__global__ __launch_bounds__(128) void k_qkv(const float* __restrict__ xp,
    const float* __restrict__ Wq, const float* __restrict__ bq,
    const float* __restrict__ Wk, const float* __restrict__ bk,
    const float* __restrict__ Wv, const float* __restrict__ bv,
    float* __restrict__ q, float* __restrict__ k, float* __restrict__ v) {
  __shared__ float xs[16][128];
  int e = threadIdx.x, n0 = blockIdx.x * 16;
#pragma unroll
  for (int n = 0; n < 16; n++) xs[n][e] = xp[(n0 + n) * 128 + e];
  __syncthreads();
  float aq[16], ak[16], av[16];
  float bqv = bq[e], bkv = bk[e], bvv = bv[e];
#pragma unroll
  for (int n = 0; n < 16; n++) { aq[n] = bqv; ak[n] = bkv; av[n] = bvv; }
  for (int a = 0; a < 128; a++) {
    float wq = Wq[a * 128 + e], wk = Wk[a * 128 + e], wv = Wv[a * 128 + e];
#pragma unroll
    for (int n = 0; n < 16; n++) {
      float xv = xs[n][a];
      aq[n] += xv * wq; ak[n] += xv * wk; av[n] += xv * wv;
    }
  }
#pragma unroll
  for (int n = 0; n < 16; n++) {
    q[(n0 + n) * 128 + e] = aq[n];
    k[(n0 + n) * 128 + e] = ak[n];
    v[(n0 + n) * 128 + e] = av[n];
  }
}

// attention for one (b, h): scores clipped to [-10,10] => exp() without max-sub
__global__ __launch_bounds__(128) void k_attn(const float* __restrict__ q,
    const float* __restrict__ kk, const float* __restrict__ vv,
    const float* __restrict__ db, float* __restrict__ oatt) {
  __shared__ float ks[128][16], vs[128][16];
  int bh = blockIdx.x, b = bh >> 3, h = bh & 7;
  int i = threadIdx.x;
  const float* kr = kk + (b * 128 + i) * 128 + h * 16;
  const float* vr = vv + (b * 128 + i) * 128 + h * 16;
#pragma unroll
  for (int d = 0; d < 16; d++) { ks[i][d] = kr[d]; vs[i][d] = vr[d]; }
  float qr[16];
  const float* qp = q + (b * 128 + i) * 128 + h * 16;
#pragma unroll
  for (int d = 0; d < 16; d++) qr[d] = qp[d];
  __syncthreads();
  const float* dbr = db + b * 16384 + i * 128;
  float rsum = 0.0f, o[16] = {};
  for (int j = 0; j < 128; j++) {
    float s = 0.0f;
#pragma unroll
    for (int d = 0; d < 16; d++) s += qr[d] * ks[j][d];
    s = s * 0.25f + dbr[j];                    // 1/sqrt(16) = 0.25
    s = fminf(10.0f, fmaxf(-10.0f, s));
    float p = __expf(s);                        // bounded by e^10, safe
    rsum += p;
#pragma unroll
    for (int d = 0; d < 16; d++) o[d] += p * vs[j][d];
  }
  float r = 1.0f / rsum;
  float* op = oatt + (b * 128 + i) * 128 + h * 16;
#pragma unroll
  for (int d = 0; d < 16; d++) op[d] = o[d] * r;
}

// out = in @ W[128,128] + bias (+res) ; optional relu
template <int RELU>
__global__ __launch_bounds__(128) void k_gemm128(const float* __restrict__ in,
    const float* __restrict__ W, const float* __restrict__ bias,
    const float* __restrict__ res, float* __restrict__ out) {
  __shared__ float xs[16][128];
  int e = threadIdx.x, n0 = blockIdx.x * 16;
#pragma unroll
  for (int n = 0; n < 16; n++) xs[n][e] = in[(n0 + n) * 128 + e];
  __syncthreads();
  float acc[16];
  float bv = bias[e];
#pragma unroll
  for (int n = 0; n < 16; n++) acc[n] = bv;
  for (int a = 0; a < 128; a++) {
    float w = W[a * 128 + e];
#pragma unroll
    for (int n = 0; n < 16; n++) acc[n] += xs[n][a] * w;
  }
#pragma unroll
  for (int n = 0; n < 16; n++) {
    float v = acc[n];
    if (res) v += res[(n0 + n) * 128 + e];
    if (RELU) v = fmaxf(v, 0.0f);
    out[(n0 + n) * 128 + e] = v;
  }
}

// ff1 = relu(x1 @ W1[128,256] + bf1)
__global__ __launch_bounds__(256) void k_ffn1(const float* __restrict__ in,
    const float* __restrict__ W, const float* __restrict__ bias, float* __restrict__ out) {
  __shared__ float xs[16][128];
  int e = threadIdx.x, n0 = blockIdx.x * 16;
#pragma unroll
  for (int i = 0; i < 8; i++) {
    int j = e + i * 256;
    xs[j >> 7][j & 127] = in[n0 * 128 + j];
  }
  __syncthreads();
  float acc[16];
  float bv = bias[e];
#pragma unroll
  for (int n = 0; n < 16; n++) acc[n] = bv;
  for (int a = 0; a < 128; a++) {
    float w = W[a * 256 + e];
#pragma unroll
    for (int n = 0; n < 16; n++) acc[n] += xs[n][a] * w;
  }
#pragma unroll
  for (int n = 0; n < 16; n++)
    out[(n0 + n) * 256 + e] = fmaxf(acc[n], 0.0f);
}

// x2pre = x1 + ff1 @ W2[256,128] + bf2
__global__ __launch_bounds__(128) void k_ffn2(const float* __restrict__ in,
    const float* __restrict__ W, const float* __restrict__ bias,
    const float* __restrict__ res, float* __restrict__ out) {
  __shared__ float xs[16][256];
  int e = threadIdx.x, n0 = blockIdx.x * 16;
#pragma unroll
  for (int i = 0; i < 32; i++) {
    int j = e + i * 128;
    xs[j >> 8][j & 255] = in[n0 * 256 + j];
  }
  __syncthreads();
  float acc[16];
  float bv = bias[e];
#pragma unroll
  for (int n = 0; n < 16; n++) acc[n] = bv;
  for (int a = 0; a < 256; a++) {
    float w = W[a * 128 + e];
#pragma unroll
    for (int n = 0; n < 16; n++) acc[n] += xs[n][a] * w;
  }
#pragma unroll
  for (int n = 0; n < 16; n++)
    out[(n0 + n) * 128 + e] = acc[n] + res[(n0 + n) * 128 + e];
}

// out[b,e] = mean over nodes
__global__ __launch_bounds__(128) void k_pool(const float* __restrict__ xp, float* __restrict__ out) {
  int b = blockIdx.x, e = threadIdx.x;
  float s = 0.0f;
  for (int n = 0; n < 128; n++) s += xp[(b * 128 + n) * 128 + e];
  out[b * 128 + e] = s * (1.0f / 128.0f);   // 128 + 1e-8 == 128.0f in fp32
}

extern "C" void kernel_launch(void* const* d_in, const int* in_sizes, int n_in,
                              void* d_out, int out_size, void* d_ws, size_t ws_size,
                              hipStream_t stream) {
  const float* x     = (const float*)d_in[0];
  const int*   ei    = (const int*)  d_in[1];
  const float* ea    = (const float*)d_in[2];
  const float* pos   = (const float*)d_in[3];
  // d_in[4] = batch (unused: contiguous equal-size graphs)
  const float* Wproj = (const float*)d_in[5];
  const float* bproj = (const float*)d_in[6];
  const float* Wlin  = (const float*)d_in[7];
  const float* blin  = (const float*)d_in[8];
  const float* g_en  = (const float*)d_in[9];
  const float* b_en  = (const float*)d_in[10];
  const float* Wq    = (const float*)d_in[11];
  const float* Wk    = (const float*)d_in[12];
  const float* Wv    = (const float*)d_in[13];
  const float* Wo    = (const float*)d_in[14];
  const float* bq    = (const float*)d_in[15];
  const float* bk    = (const float*)d_in[16];
  const float* bv    = (const float*)d_in[17];
  const float* bo    = (const float*)d_in[18];
  const float* g1    = (const float*)d_in[19];
  const float* b1    = (const float*)d_in[20];
  const float* W1    = (const float*)d_in[21];
  const float* bf1   = (const float*)d_in[22];
  const float* W2    = (const float*)d_in[23];
  const float* bf2   = (const float*)d_in[24];
  const float* g2    = (const float*)d_in[25];
  const float* b2    = (const float*)d_in[26];

  float* ws    = (float*)d_ws;
  float* ea2   = ws;                  // 16384*48   = 786432
  float* hbuf  = ea2   + 786432;      // 4096*128   = 524288
  float* agg   = hbuf  + 524288;
  float* db    = agg   + 524288;
  float* xp    = db    + 524288;
  float* qb    = xp    + 524288;
  float* kb    = qb    + 524288;
  float* vb    = kb    + 524288;
  float* oatt  = vb    + 524288;
  float* x1pre = oatt  + 524288;
  float* x1    = x1pre + 524288;
  float* ff1   = x1    + 524288;      // 4096*256   = 1048576
  float* x2pre = ff1   + 1048576;

  k_zero<<<2048, 256, 0, stream>>>(agg, 4096 * 128);
  k_node_proj<<<4096, 128, 0, stream>>>(x, Wproj, bproj, hbuf);
  k_rbf<<<3072, 256, 0, stream>>>(ea, ea2);
  k_edge_gemm<<<256, 256, 0, stream>>>(ea2, ei, hbuf, Wlin, blin, agg);
  k_ln<<<4096, 128, 0, stream>>>(agg, hbuf, g_en, b_en, xp);
  k_dist<<<4096, 128, 0, stream>>>(pos, db);

  for (int l = 0; l < 4; l++) {
    k_qkv<<<256, 128, 0, stream>>>(xp,
        Wq + l * 16384, bq + l * 128,
        Wk + l * 16384, bk + l * 128,
        Wv + l * 16384, bv + l * 128,
        qb, kb, vb);
    k_attn<<<256, 128, 0, stream>>>(qb, kb, vb, db, oatt);
    k_gemm128<0><<<256, 128, 0, stream>>>(oatt, Wo + l * 16384, bo + l * 128, xp, x1pre);
    k_ln<<<4096, 128, 0, stream>>>(x1pre, nullptr, g1 + l * 128, b1 + l * 128, x1);
    k_ffn1<<<256, 256, 0, stream>>>(x1, W1 + l * 32768, bf1 + l * 256, ff1);
    k_ffn2<<<256, 128, 0, stream>>>(ff1, W2 + l * 32768, bf2 + l * 128, x1, x2pre);
    k_ln<<<4096, 128, 0, stream>>>(x2pre, nullptr, g2 + l * 128, b2 + l * 128, xp);
  }

  k_pool<<<32, 128, 0, stream>>>(xp, (float*)d_out);
}

// Round 3
// 613.461 us; speedup vs baseline: 1.8152x; 1.8152x over previous
//
#include <hip/hip_runtime.h>

// ---------------------------------------------------------------------------
// GraphEncoder: B=32 x N=128 nodes, E=128, H=8, DH=16, L=4, M=16384 edges.
// Round 3: edge network refactored T[n,c,e]=h@Wc (bf16 MFMA, 6.4 GFLOP)
//          + gather-contract over edges (0.2 GFLOP). 4x fewer FLOPs than the
//          edge-wise GEMM and on the matrix pipe instead of fp32 VALU.
// ---------------------------------------------------------------------------

typedef __attribute__((ext_vector_type(8))) short bf16x8;
typedef __attribute__((ext_vector_type(4))) float f32x4;
#define MFMA16(a, b, c) __builtin_amdgcn_mfma_f32_16x16x32_bf16(a, b, c, 0, 0, 0)

__device__ inline unsigned short f2bf(float f) {          // RTNE
  unsigned u = __float_as_uint(f);
  u = (u + 0x7FFF + ((u >> 16) & 1)) >> 16;
  return (unsigned short)u;
}
__device__ inline unsigned pack2(float a, float b) {
  return (unsigned)f2bf(a) | ((unsigned)f2bf(b) << 16);
}
__device__ inline float bf2f(unsigned short v) {
  return __uint_as_float(((unsigned)v) << 16);
}

__global__ __launch_bounds__(256) void k_zero(float* __restrict__ p, int n) {
  int i = blockIdx.x * 256 + threadIdx.x;
  if (i < n) p[i] = 0.0f;
}

// h[n,e] = x[n,:64] @ Wproj[:,e] + bproj[e]; also bf16 copy for MFMA
__global__ __launch_bounds__(128) void k_node_proj(const float* __restrict__ x,
    const float* __restrict__ W, const float* __restrict__ b,
    float* __restrict__ h, unsigned short* __restrict__ hb) {
  __shared__ float xs[64];
  int n = blockIdx.x, e = threadIdx.x;
  if (e < 64) xs[e] = x[n * 64 + e];
  __syncthreads();
  float acc = b[e];
#pragma unroll
  for (int a = 0; a < 64; a++) acc += xs[a] * W[a * 128 + e];
  h[n * 128 + e] = acc;
  hb[n * 128 + e] = f2bf(acc);
}

// ea2[m, 0:15]=ea[m,0:15]; [15:47]=RBF(dist); [47]=1.0 (bias channel)
__global__ __launch_bounds__(256) void k_rbf(const float* __restrict__ ea, float* __restrict__ ea2) {
  int idx = blockIdx.x * 256 + threadIdx.x;  // covers M*48
  int m = idx / 48, c = idx % 48;
  float v;
  if (c < 15) {
    v = ea[m * 16 + c];
  } else if (c < 47) {
    int i = c - 15;
    float d = fminf(10.0f, fmaxf(0.0f, ea[m * 16 + 15]));
    float diff = d - 5.0f * (float)i / 31.0f;   // linspace(0,5,32)
    v = __expf(-38.44f * diff * diff);           // gamma = (31/5)^2
  } else {
    v = 1.0f;
  }
  ea2[m * 48 + c] = v;
}

// wb[c][i] = bf16(Wlin[c][i]) for c<47 ; wb[47][i] = bf16(blin[i])
__global__ __launch_bounds__(256) void k_prep_w(const float* __restrict__ Wlin,
    const float* __restrict__ blin, unsigned short* __restrict__ wb) {
  int i = blockIdx.x * 256 + threadIdx.x;     // 0..786431
  float v = (i < 770048) ? Wlin[i] : blin[i - 770048];
  wb[i] = f2bf(v);
}

// T[n][c][e] = sum_f hb[n,f] * wb[c][e*128+f]   (bf16 out, fp32 MFMA accum)
// grid: 48 c x 32 node-tiles; block 256 thr = 4 waves; per-block 128n x 128e.
// LDS tiles XOR-swizzled in 16B chunks: chunk' = chunk ^ (row&7)  [G4 recipe]
__global__ __launch_bounds__(256) void k_tbuild(const unsigned short* __restrict__ hb,
    const unsigned short* __restrict__ wb, unsigned short* __restrict__ T) {
  __shared__ unsigned short hs[16384];   // [node][f] swizzled (32 KB)
  __shared__ unsigned short wsm[16384];  // [e][f]   swizzled (32 KB)
  int c = blockIdx.x >> 5;
  int n0 = (blockIdx.x & 31) << 7;
  int t = threadIdx.x;
  const uint4* hg = (const uint4*)hb + n0 * 16;   // 16 chunks/row
  const uint4* wg = (const uint4*)wb + c * 2048;
  uint4* hs4 = (uint4*)hs;
  uint4* ws4 = (uint4*)wsm;
#pragma unroll
  for (int i = 0; i < 8; i++) {
    int q = t + i * 256;                  // 0..2047
    int row = q >> 4, ch = q & 15;
    int d = row * 16 + (ch ^ (row & 7));
    hs4[d] = hg[q];
    ws4[d] = wg[q];
  }
  __syncthreads();
  int w = t >> 6, l = t & 63;
  int lr = l & 15, lg = l >> 4;
  f32x4 acc[2][8];
#pragma unroll
  for (int et = 0; et < 2; et++)
#pragma unroll
    for (int n = 0; n < 8; n++) acc[et][n] = (f32x4){0.f, 0.f, 0.f, 0.f};
  // A = Wt rows (e), B = h cols (node)  => D[row=e][col=node]
#pragma unroll
  for (int s = 0; s < 4; s++) {
    bf16x8 af[2];
#pragma unroll
    for (int et = 0; et < 2; et++) {
      int er = w * 32 + et * 16 + lr;
      int ch = (s * 4 + lg) ^ (er & 7);
      af[et] = *(const bf16x8*)&wsm[(er * 16 + ch) * 8];
    }
#pragma unroll
    for (int n = 0; n < 8; n++) {
      int nr = n * 16 + lr;
      int ch = (s * 4 + lg) ^ (nr & 7);
      bf16x8 bfr = *(const bf16x8*)&hs[(nr * 16 + ch) * 8];
      acc[0][n] = MFMA16(af[0], bfr, acc[0][n]);
      acc[1][n] = MFMA16(af[1], bfr, acc[1][n]);
    }
  }
  // C/D layout (m89): col = lane&15 (node), row = (lane>>4)*4 + reg (e)
#pragma unroll
  for (int et = 0; et < 2; et++)
#pragma unroll
    for (int n = 0; n < 8; n++) {
      int node = n0 + n * 16 + lr;
      int e0 = w * 32 + et * 16 + lg * 4;
      uint2 pk;
      pk.x = pack2(acc[et][n][0], acc[et][n][1]);
      pk.y = pack2(acc[et][n][2], acc[et][n][3]);
      *(uint2*)&T[node * 6144 + c * 128 + e0] = pk;
    }
}

// msg[m,e] = sum_c ea2[m,c] * T[src(m)][c][e] ; atomicAdd into agg[dst(m),e]
__global__ __launch_bounds__(128) void k_contract(const float* __restrict__ ea2,
    const int* __restrict__ ei, const unsigned short* __restrict__ T,
    float* __restrict__ agg) {
  int m = blockIdx.x, e = threadIdx.x;
  int src = ei[16384 + m], dst = ei[m];
  __shared__ float ec[48];
  if (e < 48) ec[e] = ea2[m * 48 + e];
  __syncthreads();
  const unsigned short* Ts = T + src * 6144;
  float acc = 0.0f;
#pragma unroll 6
  for (int c = 0; c < 48; c++) acc += ec[c] * bf2f(Ts[c * 128 + e]);
  atomicAdd(&agg[dst * 128 + e], acc);
}

// out[n,:] = LN(in[n,:] (+ res[n,:])) * g + b
__global__ __launch_bounds__(128) void k_ln(const float* __restrict__ in,
    const float* __restrict__ res, const float* __restrict__ g,
    const float* __restrict__ b, float* __restrict__ out) {
  int n = blockIdx.x, e = threadIdx.x;
  float v = in[n * 128 + e];
  if (res) v += res[n * 128 + e];
  float s = v, s2 = v * v;
#pragma unroll
  for (int o = 1; o < 64; o <<= 1) { s += __shfl_xor(s, o); s2 += __shfl_xor(s2, o); }
  __shared__ float r0[2], r1[2];
  int wid = e >> 6;
  if ((e & 63) == 0) { r0[wid] = s; r1[wid] = s2; }
  __syncthreads();
  float ts = r0[0] + r0[1], ts2 = r1[0] + r1[1];
  float mu = ts * (1.0f / 128.0f);
  float var = fmaxf(ts2 * (1.0f / 128.0f) - mu * mu, 0.0f);
  float inv = rsqrtf(var + 1e-5f);
  out[n * 128 + e] = (v - mu) * inv * g[e] + b[e];
}

// pairwise distances per graph
__global__ __launch_bounds__(128) void k_dist(const float* __restrict__ pos, float* __restrict__ db) {
  int bi = blockIdx.x;
  int b = bi >> 7, i = bi & 127, j = threadIdx.x;
  float x0 = pos[(b * 128 + i) * 3 + 0];
  float y0 = pos[(b * 128 + i) * 3 + 1];
  float z0 = pos[(b * 128 + i) * 3 + 2];
  float dx = x0 - pos[(b * 128 + j) * 3 + 0];
  float dy = y0 - pos[(b * 128 + j) * 3 + 1];
  float dz = z0 - pos[(b * 128 + j) * 3 + 2];
  float d2 = dx * dx + dy * dy + dz * dz;
  db[b * 16384 + i * 128 + j] = (d2 > 0.0f) ? sqrtf(d2) : 0.0f;
}

// q/k/v = xp @ W* + b*
__global__ __launch_bounds__(128) void k_qkv(const float* __restrict__ xp,
    const float* __restrict__ Wq, const float* __restrict__ bq,
    const float* __restrict__ Wk, const float* __restrict__ bk,
    const float* __restrict__ Wv, const float* __restrict__ bv,
    float* __restrict__ q, float* __restrict__ k, float* __restrict__ v) {
  __shared__ float xs[16][128];
  int e = threadIdx.x, n0 = blockIdx.x * 16;
#pragma unroll
  for (int n = 0; n < 16; n++) xs[n][e] = xp[(n0 + n) * 128 + e];
  __syncthreads();
  float aq[16], ak[16], av[16];
  float bqv = bq[e], bkv = bk[e], bvv = bv[e];
#pragma unroll
  for (int n = 0; n < 16; n++) { aq[n] = bqv; ak[n] = bkv; av[n] = bvv; }
  for (int a = 0; a < 128; a++) {
    float wq = Wq[a * 128 + e], wk = Wk[a * 128 + e], wv = Wv[a * 128 + e];
#pragma unroll
    for (int n = 0; n < 16; n++) {
      float xv = xs[n][a];
      aq[n] += xv * wq; ak[n] += xv * wk; av[n] += xv * wv;
    }
  }
#pragma unroll
  for (int n = 0; n < 16; n++) {
    q[(n0 + n) * 128 + e] = aq[n];
    k[(n0 + n) * 128 + e] = ak[n];
    v[(n0 + n) * 128 + e] = av[n];
  }
}

// attention for one (b,h): scores clipped to [-10,10] => exp without max-sub
__global__ __launch_bounds__(128) void k_attn(const float* __restrict__ q,
    const float* __restrict__ kk, const float* __restrict__ vv,
    const float* __restrict__ db, float* __restrict__ oatt) {
  __shared__ float ks[128][16], vs[128][16];
  int bh = blockIdx.x, b = bh >> 3, h = bh & 7;
  int i = threadIdx.x;
  const float* kr = kk + (b * 128 + i) * 128 + h * 16;
  const float* vr = vv + (b * 128 + i) * 128 + h * 16;
#pragma unroll
  for (int d = 0; d < 16; d++) { ks[i][d] = kr[d]; vs[i][d] = vr[d]; }
  float qr[16];
  const float* qp = q + (b * 128 + i) * 128 + h * 16;
#pragma unroll
  for (int d = 0; d < 16; d++) qr[d] = qp[d];
  __syncthreads();
  const float* dbr = db + b * 16384 + i * 128;
  float rsum = 0.0f, o[16] = {};
  for (int j = 0; j < 128; j++) {
    float s = 0.0f;
#pragma unroll
    for (int d = 0; d < 16; d++) s += qr[d] * ks[j][d];
    s = s * 0.25f + dbr[j];
    s = fminf(10.0f, fmaxf(-10.0f, s));
    float p = __expf(s);
    rsum += p;
#pragma unroll
    for (int d = 0; d < 16; d++) o[d] += p * vs[j][d];
  }
  float r = 1.0f / rsum;
  float* op = oatt + (b * 128 + i) * 128 + h * 16;
#pragma unroll
  for (int d = 0; d < 16; d++) op[d] = o[d] * r;
}

template <int RELU>
__global__ __launch_bounds__(128) void k_gemm128(const float* __restrict__ in,
    const float* __restrict__ W, const float* __restrict__ bias,
    const float* __restrict__ res, float* __restrict__ out) {
  __shared__ float xs[16][128];
  int e = threadIdx.x, n0 = blockIdx.x * 16;
#pragma unroll
  for (int n = 0; n < 16; n++) xs[n][e] = in[(n0 + n) * 128 + e];
  __syncthreads();
  float acc[16];
  float bv = bias[e];
#pragma unroll
  for (int n = 0; n < 16; n++) acc[n] = bv;
  for (int a = 0; a < 128; a++) {
    float w = W[a * 128 + e];
#pragma unroll
    for (int n = 0; n < 16; n++) acc[n] += xs[n][a] * w;
  }
#pragma unroll
  for (int n = 0; n < 16; n++) {
    float v = acc[n];
    if (res) v += res[(n0 + n) * 128 + e];
    if (RELU) v = fmaxf(v, 0.0f);
    out[(n0 + n) * 128 + e] = v;
  }
}

__global__ __launch_bounds__(256) void k_ffn1(const float* __restrict__ in,
    const float* __restrict__ W, const float* __restrict__ bias, float* __restrict__ out) {
  __shared__ float xs[16][128];
  int e = threadIdx.x, n0 = blockIdx.x * 16;
#pragma unroll
  for (int i = 0; i < 8; i++) {
    int j = e + i * 256;
    xs[j >> 7][j & 127] = in[n0 * 128 + j];
  }
  __syncthreads();
  float acc[16];
  float bv = bias[e];
#pragma unroll
  for (int n = 0; n < 16; n++) acc[n] = bv;
  for (int a = 0; a < 128; a++) {
    float w = W[a * 256 + e];
#pragma unroll
    for (int n = 0; n < 16; n++) acc[n] += xs[n][a] * w;
  }
#pragma unroll
  for (int n = 0; n < 16; n++)
    out[(n0 + n) * 256 + e] = fmaxf(acc[n], 0.0f);
}

__global__ __launch_bounds__(128) void k_ffn2(const float* __restrict__ in,
    const float* __restrict__ W, const float* __restrict__ bias,
    const float* __restrict__ res, float* __restrict__ out) {
  __shared__ float xs[16][256];
  int e = threadIdx.x, n0 = blockIdx.x * 16;
#pragma unroll
  for (int i = 0; i < 32; i++) {
    int j = e + i * 128;
    xs[j >> 8][j & 255] = in[n0 * 256 + j];
  }
  __syncthreads();
  float acc[16];
  float bv = bias[e];
#pragma unroll
  for (int n = 0; n < 16; n++) acc[n] = bv;
  for (int a = 0; a < 256; a++) {
    float w = W[a * 128 + e];
#pragma unroll
    for (int n = 0; n < 16; n++) acc[n] += xs[n][a] * w;
  }
#pragma unroll
  for (int n = 0; n < 16; n++)
    out[(n0 + n) * 128 + e] = acc[n] + res[(n0 + n) * 128 + e];
}

__global__ __launch_bounds__(128) void k_pool(const float* __restrict__ xp, float* __restrict__ out) {
  int b = blockIdx.x, e = threadIdx.x;
  float s = 0.0f;
  for (int n = 0; n < 128; n++) s += xp[(b * 128 + n) * 128 + e];
  out[b * 128 + e] = s * (1.0f / 128.0f);
}

extern "C" void kernel_launch(void* const* d_in, const int* in_sizes, int n_in,
                              void* d_out, int out_size, void* d_ws, size_t ws_size,
                              hipStream_t stream) {
  const float* x     = (const float*)d_in[0];
  const int*   ei    = (const int*)  d_in[1];
  const float* ea    = (const float*)d_in[2];
  const float* pos   = (const float*)d_in[3];
  const float* Wproj = (const float*)d_in[5];
  const float* bproj = (const float*)d_in[6];
  const float* Wlin  = (const float*)d_in[7];
  const float* blin  = (const float*)d_in[8];
  const float* g_en  = (const float*)d_in[9];
  const float* b_en  = (const float*)d_in[10];
  const float* Wq    = (const float*)d_in[11];
  const float* Wk    = (const float*)d_in[12];
  const float* Wv    = (const float*)d_in[13];
  const float* Wo    = (const float*)d_in[14];
  const float* bq    = (const float*)d_in[15];
  const float* bk    = (const float*)d_in[16];
  const float* bv    = (const float*)d_in[17];
  const float* bo    = (const float*)d_in[18];
  const float* g1    = (const float*)d_in[19];
  const float* b1    = (const float*)d_in[20];
  const float* W1    = (const float*)d_in[21];
  const float* bf1   = (const float*)d_in[22];
  const float* W2    = (const float*)d_in[23];
  const float* bf2   = (const float*)d_in[24];
  const float* g2    = (const float*)d_in[25];
  const float* b2    = (const float*)d_in[26];

  float* ws = (float*)d_ws;
  // ---- region A (live through edge phase) : 9.5 MB ----
  float* ea2  = ws;                          // 786432 f
  float* hbuf = ea2  + 786432;               // 524288 f
  float* agg  = hbuf + 524288;               // 524288 f
  unsigned short* hbf = (unsigned short*)(agg + 524288);    // 4096*128 bf16
  unsigned short* wbf = hbf + 524288;                        // 48*16384 bf16
  // ---- region B: T [4096][48][128] bf16 = 48 MB ----
  float* base2 = ws + 2490368;
  unsigned short* Tb = (unsigned short*)base2;
  // ---- region C (layer phase) aliases T; first write happens after T dead ---
  float* db    = base2;                      // k_dist runs AFTER k_contract
  float* xp    = db    + 524288;
  float* qb    = xp    + 524288;
  float* kb    = qb    + 524288;
  float* vb    = kb    + 524288;
  float* oatt  = vb    + 524288;
  float* x1pre = oatt  + 524288;
  float* x1    = x1pre + 524288;
  float* ff1   = x1    + 524288;             // 1048576 f
  float* x2pre = ff1   + 1048576;

  k_zero<<<2048, 256, 0, stream>>>(agg, 4096 * 128);
  k_node_proj<<<4096, 128, 0, stream>>>(x, Wproj, bproj, hbuf, hbf);
  k_rbf<<<3072, 256, 0, stream>>>(ea, ea2);
  k_prep_w<<<3072, 256, 0, stream>>>(Wlin, blin, wbf);
  k_tbuild<<<1536, 256, 0, stream>>>(hbf, wbf, Tb);
  k_contract<<<16384, 128, 0, stream>>>(ea2, ei, Tb, agg);
  k_ln<<<4096, 128, 0, stream>>>(agg, hbuf, g_en, b_en, xp);
  k_dist<<<4096, 128, 0, stream>>>(pos, db);   // after contract: db aliases T

  for (int l = 0; l < 4; l++) {
    k_qkv<<<256, 128, 0, stream>>>(xp,
        Wq + l * 16384, bq + l * 128,
        Wk + l * 16384, bk + l * 128,
        Wv + l * 16384, bv + l * 128,
        qb, kb, vb);
    k_attn<<<256, 128, 0, stream>>>(qb, kb, vb, db, oatt);
    k_gemm128<0><<<256, 128, 0, stream>>>(oatt, Wo + l * 16384, bo + l * 128, xp, x1pre);
    k_ln<<<4096, 128, 0, stream>>>(x1pre, nullptr, g1 + l * 128, b1 + l * 128, x1);
    k_ffn1<<<256, 256, 0, stream>>>(x1, W1 + l * 32768, bf1 + l * 256, ff1);
    k_ffn2<<<256, 128, 0, stream>>>(ff1, W2 + l * 32768, bf2 + l * 128, x1, x2pre);
    k_ln<<<4096, 128, 0, stream>>>(x2pre, nullptr, g2 + l * 128, b2 + l * 128, xp);
  }

  k_pool<<<32, 128, 0, stream>>>(xp, (float*)d_out);
}

// Round 5
// 431.483 us; speedup vs baseline: 2.5808x; 1.4217x over previous
//
#include <hip/hip_runtime.h>

// ---------------------------------------------------------------------------
// GraphEncoder: B=32 x N=128, E=128, H=8, DH=16, L=4, M=16384 edges.
// Round 4/5: transformer tail on bf16 MFMA via one reusable GEMM kernel
// with fused bias/relu/residual/LayerNorm epilogues. Weights pre-transposed
// to [out][in] bf16 so MFMA fragments are k-contiguous (tbuild pattern).
// Edge phase (tbuild/contract) unchanged from round 3 (verified).
// ---------------------------------------------------------------------------

typedef __attribute__((ext_vector_type(8))) short bf16x8;
typedef __attribute__((ext_vector_type(4))) float f32x4;
#define MFMA16(a, b, c) __builtin_amdgcn_mfma_f32_16x16x32_bf16(a, b, c, 0, 0, 0)

__device__ inline unsigned short f2bf(float f) {          // RTNE
  unsigned u = __float_as_uint(f);
  u = (u + 0x7FFF + ((u >> 16) & 1)) >> 16;
  return (unsigned short)u;
}
__device__ inline unsigned pack2(float a, float b) {
  return (unsigned)f2bf(a) | ((unsigned)f2bf(b) << 16);
}
__device__ inline float bf2f(unsigned short v) {
  return __uint_as_float(((unsigned)v) << 16);
}

__global__ __launch_bounds__(256) void k_zero(float* __restrict__ p, int n) {
  int i = blockIdx.x * 256 + threadIdx.x;
  if (i < n) p[i] = 0.0f;
}

// h[n,e] = x[n,:64] @ Wproj[:,e] + bproj[e]; also bf16 copy for MFMA
__global__ __launch_bounds__(128) void k_node_proj(const float* __restrict__ x,
    const float* __restrict__ W, const float* __restrict__ b,
    float* __restrict__ h, unsigned short* __restrict__ hb) {
  __shared__ float xs[64];
  int n = blockIdx.x, e = threadIdx.x;
  if (e < 64) xs[e] = x[n * 64 + e];
  __syncthreads();
  float acc = b[e];
#pragma unroll
  for (int a = 0; a < 64; a++) acc += xs[a] * W[a * 128 + e];
  h[n * 128 + e] = acc;
  hb[n * 128 + e] = f2bf(acc);
}

// ea2[m,0:15]=ea[m,0:15]; [15:47]=RBF(dist); [47]=1.0 (bias channel)
__global__ __launch_bounds__(256) void k_rbf(const float* __restrict__ ea, float* __restrict__ ea2) {
  int idx = blockIdx.x * 256 + threadIdx.x;
  int m = idx / 48, c = idx % 48;
  float v;
  if (c < 15) {
    v = ea[m * 16 + c];
  } else if (c < 47) {
    int i = c - 15;
    float d = fminf(10.0f, fmaxf(0.0f, ea[m * 16 + 15]));
    float diff = d - 5.0f * (float)i / 31.0f;
    v = __expf(-38.44f * diff * diff);
  } else {
    v = 1.0f;
  }
  ea2[m * 48 + c] = v;
}

// wb[c][i] = bf16(Wlin[c][i]); wb[47][i] = bf16(blin[i])
__global__ __launch_bounds__(256) void k_prep_w(const float* __restrict__ Wlin,
    const float* __restrict__ blin, unsigned short* __restrict__ wb) {
  int i = blockIdx.x * 256 + threadIdx.x;
  float v = (i < 770048) ? Wlin[i] : blin[i - 770048];
  wb[i] = f2bf(v);
}

// generic [L][Kin][Nout] fp32 -> [L][Nout][Kin] bf16 transpose-convert
__global__ __launch_bounds__(256) void k_prep_t(const float* __restrict__ src,
    unsigned short* __restrict__ dst, int Kin, int Nout, int total) {
  int idx = blockIdx.x * 256 + threadIdx.x;
  if (idx >= total) return;
  int per = Kin * Nout;
  int l = idx / per, r = idx % per;
  int a = r / Nout, j = r % Nout;
  dst[l * per + j * Kin + a] = f2bf(src[idx]);
}

// qkvt[l][j][a] (j:0..383 = q|k|v cols), qkvb[l][j] = concat bias
__global__ __launch_bounds__(256) void k_prep_qkvt(const float* __restrict__ Wq,
    const float* __restrict__ Wk, const float* __restrict__ Wv,
    const float* __restrict__ bq, const float* __restrict__ bk, const float* __restrict__ bv,
    unsigned short* __restrict__ qkvt, float* __restrict__ qkvb) {
  int idx = blockIdx.x * 256 + threadIdx.x;   // 0..196607
  int l = idx / 49152, r = idx % 49152;
  int j = r / 128, a = r % 128;
  int jj = j & 127;
  const float* W = (j < 128) ? Wq : (j < 256) ? Wk : Wv;
  qkvt[idx] = f2bf(W[l * 16384 + a * 128 + jj]);
  if (a == 0) {
    const float* bb = (j < 128) ? bq : (j < 256) ? bk : bv;
    qkvb[l * 384 + j] = bb[l * 128 + jj];
  }
}

// T[n][c][e] = sum_f hb[n,f] * wb[c][e*128+f]   (verified round 3)
__global__ __launch_bounds__(256) void k_tbuild(const unsigned short* __restrict__ hb,
    const unsigned short* __restrict__ wb, unsigned short* __restrict__ T) {
  __shared__ unsigned short hs[16384];
  __shared__ unsigned short wsm[16384];
  int c = blockIdx.x >> 5;
  int n0 = (blockIdx.x & 31) << 7;
  int t = threadIdx.x;
  const uint4* hg = (const uint4*)hb + n0 * 16;
  const uint4* wg = (const uint4*)wb + c * 2048;
  uint4* hs4 = (uint4*)hs;
  uint4* ws4 = (uint4*)wsm;
#pragma unroll
  for (int i = 0; i < 8; i++) {
    int q = t + i * 256;
    int row = q >> 4, ch = q & 15;
    int d = row * 16 + (ch ^ (row & 7));
    hs4[d] = hg[q];
    ws4[d] = wg[q];
  }
  __syncthreads();
  int w = t >> 6, l = t & 63;
  int lr = l & 15, lg = l >> 4;
  f32x4 acc[2][8];
#pragma unroll
  for (int et = 0; et < 2; et++)
#pragma unroll
    for (int n = 0; n < 8; n++) acc[et][n] = (f32x4){0.f, 0.f, 0.f, 0.f};
#pragma unroll
  for (int s = 0; s < 4; s++) {
    bf16x8 af[2];
#pragma unroll
    for (int et = 0; et < 2; et++) {
      int er = w * 32 + et * 16 + lr;
      int ch = (s * 4 + lg) ^ (er & 7);
      af[et] = *(const bf16x8*)&wsm[(er * 16 + ch) * 8];
    }
#pragma unroll
    for (int n = 0; n < 8; n++) {
      int nr = n * 16 + lr;
      int ch = (s * 4 + lg) ^ (nr & 7);
      bf16x8 bfr = *(const bf16x8*)&hs[(nr * 16 + ch) * 8];
      acc[0][n] = MFMA16(af[0], bfr, acc[0][n]);
      acc[1][n] = MFMA16(af[1], bfr, acc[1][n]);
    }
  }
#pragma unroll
  for (int et = 0; et < 2; et++)
#pragma unroll
    for (int n = 0; n < 8; n++) {
      int node = n0 + n * 16 + lr;
      int e0 = w * 32 + et * 16 + lg * 4;
      uint2 pk;
      pk.x = pack2(acc[et][n][0], acc[et][n][1]);
      pk.y = pack2(acc[et][n][2], acc[et][n][3]);
      *(uint2*)&T[node * 6144 + c * 128 + e0] = pk;
    }
}

// msg[m,e] = sum_c ea2[m,c]*T[src][c][e]; atomicAdd agg[dst,e]
__global__ __launch_bounds__(128) void k_contract(const float* __restrict__ ea2,
    const int* __restrict__ ei, const unsigned short* __restrict__ T,
    float* __restrict__ agg) {
  int m = blockIdx.x, e = threadIdx.x;
  int src = ei[16384 + m], dst = ei[m];
  __shared__ float ec[48];
  if (e < 48) ec[e] = ea2[m * 48 + e];
  __syncthreads();
  const unsigned short* Ts = T + src * 6144;
  float acc = 0.0f;
#pragma unroll 6
  for (int c = 0; c < 48; c++) acc += ec[c] * bf2f(Ts[c * 128 + e]);
  atomicAdd(&agg[dst * 128 + e], acc);
}

// standalone LN (edge-network epilogue only)
__global__ __launch_bounds__(128) void k_ln(const float* __restrict__ in,
    const float* __restrict__ res, const float* __restrict__ g,
    const float* __restrict__ b, float* __restrict__ out) {
  int n = blockIdx.x, e = threadIdx.x;
  float v = in[n * 128 + e];
  if (res) v += res[n * 128 + e];
  float s = v, s2 = v * v;
#pragma unroll
  for (int o = 1; o < 64; o <<= 1) { s += __shfl_xor(s, o); s2 += __shfl_xor(s2, o); }
  __shared__ float r0[2], r1[2];
  int wid = e >> 6;
  if ((e & 63) == 0) { r0[wid] = s; r1[wid] = s2; }
  __syncthreads();
  float ts = r0[0] + r0[1], ts2 = r1[0] + r1[1];
  float mu = ts * (1.0f / 128.0f);
  float var = fmaxf(ts2 * (1.0f / 128.0f) - mu * mu, 0.0f);
  float inv = rsqrtf(var + 1e-5f);
  out[n * 128 + e] = (v - mu) * inv * g[e] + b[e];
}

__global__ __launch_bounds__(128) void k_dist(const float* __restrict__ pos, float* __restrict__ db) {
  int bi = blockIdx.x;
  int b = bi >> 7, i = bi & 127, j = threadIdx.x;
  float x0 = pos[(b * 128 + i) * 3 + 0];
  float y0 = pos[(b * 128 + i) * 3 + 1];
  float z0 = pos[(b * 128 + i) * 3 + 2];
  float dx = x0 - pos[(b * 128 + j) * 3 + 0];
  float dy = y0 - pos[(b * 128 + j) * 3 + 1];
  float dz = z0 - pos[(b * 128 + j) * 3 + 2];
  float d2 = dx * dx + dy * dy + dz * dz;
  db[b * 16384 + i * 128 + j] = (d2 > 0.0f) ? sqrtf(d2) : 0.0f;
}

// ---------------------------------------------------------------------------
// Reusable MFMA GEMM: out[node][n0+e] = epi(A[node][:K] @ Bt[n0+e][:K])
//   A fp32 [M=4096][K], Bt bf16 [Ntot][K] pre-transposed.
//   Tile 128 nodes x 128 cols, K in KCH chunks of 128. 4 waves.
//   epi: +bias[n0+e], optional relu, optional +res[node][e], optional LN.
//   LN requires grid.y==1 (full 128-col row per block).
// ---------------------------------------------------------------------------
template <int RELU, int RES, int LN, int KCH>
__global__ __launch_bounds__(256) void k_gemm(
    const float* __restrict__ A, const unsigned short* __restrict__ Bt,
    const float* __restrict__ bias, const float* __restrict__ res,
    const float* __restrict__ g, const float* __restrict__ bb,
    float* __restrict__ out, int ldc) {
  constexpr int K = KCH * 128;
  __shared__ unsigned short As[16384];
  __shared__ unsigned short Bs[16384];
  __shared__ float red[2][4][128];
  int t = threadIdx.x;
  int m0 = blockIdx.x << 7;
  int n0 = blockIdx.y << 7;
  uint4* As4 = (uint4*)As;
  uint4* Bs4 = (uint4*)Bs;
  int w = t >> 6, l = t & 63;
  int lr = l & 15, lg = l >> 4;

  f32x4 acc[2][8];
#pragma unroll
  for (int et = 0; et < 2; et++)
#pragma unroll
    for (int n = 0; n < 8; n++) acc[et][n] = (f32x4){0.f, 0.f, 0.f, 0.f};

  for (int kc = 0; kc < KCH; kc++) {
    if (kc) __syncthreads();
#pragma unroll
    for (int i = 0; i < 8; i++) {
      int q = t + i * 256;
      int row = q >> 4, ch = q & 15;
      int d = row * 16 + (ch ^ (row & 7));
      const float* ap = A + (size_t)(m0 + row) * K + kc * 128 + ch * 8;
      float4 fa = *(const float4*)ap;
      float4 fb = *(const float4*)(ap + 4);
      uint4 pk;
      pk.x = pack2(fa.x, fa.y); pk.y = pack2(fa.z, fa.w);
      pk.z = pack2(fb.x, fb.y); pk.w = pack2(fb.z, fb.w);
      As4[d] = pk;
      Bs4[d] = *((const uint4*)(Bt + (size_t)(n0 + row) * K + kc * 128) + ch);
    }
    __syncthreads();
#pragma unroll
    for (int s = 0; s < 4; s++) {
      bf16x8 af[2];
#pragma unroll
      for (int et = 0; et < 2; et++) {
        int er = w * 32 + et * 16 + lr;
        int ch = (s * 4 + lg) ^ (er & 7);
        af[et] = *(const bf16x8*)&Bs[(er * 16 + ch) * 8];
      }
#pragma unroll
      for (int n = 0; n < 8; n++) {
        int nr = n * 16 + lr;
        int ch = (s * 4 + lg) ^ (nr & 7);
        bf16x8 bfr = *(const bf16x8*)&As[(nr * 16 + ch) * 8];
        acc[0][n] = MFMA16(af[0], bfr, acc[0][n]);
        acc[1][n] = MFMA16(af[1], bfr, acc[1][n]);
      }
    }
  }

  // epilogue. D layout: col(node-sub)=lr, rows e = w*32+et*16+lg*4+reg.
  float4 b4[2];
#pragma unroll
  for (int et = 0; et < 2; et++)
    b4[et] = *(const float4*)&bias[n0 + w * 32 + et * 16 + lg * 4];
  float v[2][8][4];
#pragma unroll
  for (int et = 0; et < 2; et++)
#pragma unroll
    for (int n = 0; n < 8; n++) {
      int node = m0 + n * 16 + lr;
      float4 rv;
      if (RES) rv = *(const float4*)&res[(size_t)node * 128 + w * 32 + et * 16 + lg * 4];
#pragma unroll
      for (int r = 0; r < 4; r++) {
        float x = acc[et][n][r] + ((const float*)&b4[et])[r];
        if (RELU) x = fmaxf(x, 0.0f);
        if (RES) x += ((const float*)&rv)[r];
        v[et][n][r] = x;
      }
    }

  if (LN) {
    float s[8], s2[8];
#pragma unroll
    for (int n = 0; n < 8; n++) {
      float a = 0, b2s = 0;
#pragma unroll
      for (int et = 0; et < 2; et++)
#pragma unroll
        for (int r = 0; r < 4; r++) { a += v[et][n][r]; b2s += v[et][n][r] * v[et][n][r]; }
      s[n] = a; s2[n] = b2s;
    }
#pragma unroll
    for (int off = 16; off < 64; off <<= 1)
#pragma unroll
      for (int n = 0; n < 8; n++) { s[n] += __shfl_xor(s[n], off); s2[n] += __shfl_xor(s2[n], off); }
    if (l < 16) {
#pragma unroll
      for (int n = 0; n < 8; n++) { red[0][w][n * 16 + lr] = s[n]; red[1][w][n * 16 + lr] = s2[n]; }
    }
    __syncthreads();
    float4 g4[2], bb4[2];
#pragma unroll
    for (int et = 0; et < 2; et++) {
      g4[et]  = *(const float4*)&g[w * 32 + et * 16 + lg * 4];
      bb4[et] = *(const float4*)&bb[w * 32 + et * 16 + lg * 4];
    }
#pragma unroll
    for (int n = 0; n < 8; n++) {
      int nloc = n * 16 + lr;
      float ts  = red[0][0][nloc] + red[0][1][nloc] + red[0][2][nloc] + red[0][3][nloc];
      float ts2 = red[1][0][nloc] + red[1][1][nloc] + red[1][2][nloc] + red[1][3][nloc];
      float mu = ts * (1.0f / 128.0f);
      float var = fmaxf(ts2 * (1.0f / 128.0f) - mu * mu, 0.0f);
      float inv = rsqrtf(var + 1e-5f);
      int node = m0 + nloc;
#pragma unroll
      for (int et = 0; et < 2; et++) {
        float4 ov;
#pragma unroll
        for (int r = 0; r < 4; r++)
          ((float*)&ov)[r] = (v[et][n][r] - mu) * inv * ((const float*)&g4[et])[r] + ((const float*)&bb4[et])[r];
        *(float4*)&out[(size_t)node * ldc + w * 32 + et * 16 + lg * 4] = ov;
      }
    }
  } else {
#pragma unroll
    for (int et = 0; et < 2; et++)
#pragma unroll
      for (int n = 0; n < 8; n++) {
        int node = m0 + n * 16 + lr;
        float4 ov;
#pragma unroll
        for (int r = 0; r < 4; r++) ((float*)&ov)[r] = v[et][n][r];
        *(float4*)&out[(size_t)node * ldc + n0 + w * 32 + et * 16 + lg * 4] = ov;
      }
  }
}

// attention for one (b,h); qkv packed [node][384] = q|k|v
__global__ __launch_bounds__(128) void k_attn(const float* __restrict__ qkv,
    const float* __restrict__ db, float* __restrict__ oatt) {
  __shared__ float ks[128][16], vs[128][16];
  int bh = blockIdx.x, b = bh >> 3, h = bh & 7;
  int i = threadIdx.x;
  int node = b * 128 + i;
  const float4* kr = (const float4*)(qkv + (size_t)node * 384 + 128 + h * 16);
  const float4* vr = (const float4*)(qkv + (size_t)node * 384 + 256 + h * 16);
#pragma unroll
  for (int d4 = 0; d4 < 4; d4++) {
    *(float4*)&ks[i][d4 * 4] = kr[d4];
    *(float4*)&vs[i][d4 * 4] = vr[d4];
  }
  float qr[16];
  const float4* qp = (const float4*)(qkv + (size_t)node * 384 + h * 16);
#pragma unroll
  for (int d4 = 0; d4 < 4; d4++) *(float4*)&qr[d4 * 4] = qp[d4];
  __syncthreads();
  const float4* dbr = (const float4*)(db + b * 16384 + i * 128);
  float rsum = 0.0f, o[16] = {};
  for (int j4 = 0; j4 < 32; j4++) {
    float4 dv = dbr[j4];
#pragma unroll
    for (int u = 0; u < 4; u++) {
      int j = j4 * 4 + u;
      float s = 0.0f;
#pragma unroll
      for (int d = 0; d < 16; d++) s += qr[d] * ks[j][d];
      s = s * 0.25f + ((const float*)&dv)[u];
      s = fminf(10.0f, fmaxf(-10.0f, s));
      float p = __expf(s);
      rsum += p;
#pragma unroll
      for (int d = 0; d < 16; d++) o[d] += p * vs[j][d];
    }
  }
  float r = 1.0f / rsum;
  float* op = oatt + (size_t)node * 128 + h * 16;
#pragma unroll
  for (int d4 = 0; d4 < 4; d4++)
    *(float4*)&op[d4 * 4] = make_float4(o[d4 * 4] * r, o[d4 * 4 + 1] * r, o[d4 * 4 + 2] * r, o[d4 * 4 + 3] * r);
}

__global__ __launch_bounds__(128) void k_pool(const float* __restrict__ xp, float* __restrict__ out) {
  int b = blockIdx.x, e = threadIdx.x;
  float s = 0.0f;
  for (int n = 0; n < 128; n++) s += xp[(b * 128 + n) * 128 + e];
  out[b * 128 + e] = s * (1.0f / 128.0f);
}

extern "C" void kernel_launch(void* const* d_in, const int* in_sizes, int n_in,
                              void* d_out, int out_size, void* d_ws, size_t ws_size,
                              hipStream_t stream) {
  const float* x     = (const float*)d_in[0];
  const int*   ei    = (const int*)  d_in[1];
  const float* ea    = (const float*)d_in[2];
  const float* pos   = (const float*)d_in[3];
  const float* Wproj = (const float*)d_in[5];
  const float* bproj = (const float*)d_in[6];
  const float* Wlin  = (const float*)d_in[7];
  const float* blin  = (const float*)d_in[8];
  const float* g_en  = (const float*)d_in[9];
  const float* b_en  = (const float*)d_in[10];
  const float* Wq    = (const float*)d_in[11];
  const float* Wk    = (const float*)d_in[12];
  const float* Wv    = (const float*)d_in[13];
  const float* Wo    = (const float*)d_in[14];
  const float* bq    = (const float*)d_in[15];
  const float* bk    = (const float*)d_in[16];
  const float* bv    = (const float*)d_in[17];
  const float* bo    = (const float*)d_in[18];
  const float* g1    = (const float*)d_in[19];
  const float* b1    = (const float*)d_in[20];
  const float* W1    = (const float*)d_in[21];
  const float* bf1   = (const float*)d_in[22];
  const float* W2    = (const float*)d_in[23];
  const float* bf2   = (const float*)d_in[24];
  const float* g2    = (const float*)d_in[25];
  const float* b2    = (const float*)d_in[26];

  float* ws = (float*)d_ws;
  // region A: edge phase + prepped weights (persistent through call)
  float* ea2  = ws;                                         // 786432
  float* hbuf = ea2  + 786432;                              // 524288
  float* agg  = hbuf + 524288;                              // 524288
  unsigned short* hbf  = (unsigned short*)(agg + 524288);   // 524288 bf16
  unsigned short* wbf  = hbf + 524288;                      // 786432 bf16
  unsigned short* qkvt = wbf + 786432;                      // 196608 bf16
  unsigned short* wot  = qkvt + 196608;                     // 65536 bf16
  unsigned short* w1t  = wot + 65536;                       // 131072 bf16
  unsigned short* w2t  = w1t + 131072;                      // 131072 bf16
  float* qkvb = (float*)(w2t + 131072);                     // 1536 f
  // region B: T [4096][48][128] bf16 = 48 MB
  float* base2 = qkvb + 1536;
  unsigned short* Tb = (unsigned short*)base2;
  // region C (layer phase) aliases T; first written after T is dead
  float* db   = base2;                 // 524288
  float* xp   = db   + 524288;         // 524288
  float* qkv  = xp   + 524288;         // 1572864  [4096][384]
  float* oatt = qkv  + 1572864;        // 524288
  float* x1   = oatt + 524288;         // 524288
  float* ff1  = x1   + 524288;         // 1048576  [4096][256]

  k_zero<<<2048, 256, 0, stream>>>(agg, 4096 * 128);
  k_node_proj<<<4096, 128, 0, stream>>>(x, Wproj, bproj, hbuf, hbf);
  k_rbf<<<3072, 256, 0, stream>>>(ea, ea2);
  k_prep_w<<<3072, 256, 0, stream>>>(Wlin, blin, wbf);
  k_prep_qkvt<<<768, 256, 0, stream>>>(Wq, Wk, Wv, bq, bk, bv, qkvt, qkvb);
  k_prep_t<<<256, 256, 0, stream>>>(Wo, wot, 128, 128, 4 * 16384);
  k_prep_t<<<512, 256, 0, stream>>>(W1, w1t, 128, 256, 4 * 32768);
  k_prep_t<<<512, 256, 0, stream>>>(W2, w2t, 256, 128, 4 * 32768);
  k_tbuild<<<1536, 256, 0, stream>>>(hbf, wbf, Tb);
  k_contract<<<16384, 128, 0, stream>>>(ea2, ei, Tb, agg);
  k_ln<<<4096, 128, 0, stream>>>(agg, hbuf, g_en, b_en, xp);   // T dead; region C live
  k_dist<<<4096, 128, 0, stream>>>(pos, db);

  for (int l = 0; l < 4; l++) {
    k_gemm<0, 0, 0, 1><<<dim3(32, 3), 256, 0, stream>>>(
        xp, qkvt + l * 49152, qkvb + l * 384, nullptr, nullptr, nullptr, qkv, 384);
    k_attn<<<256, 128, 0, stream>>>(qkv, db, oatt);
    k_gemm<0, 1, 1, 1><<<dim3(32, 1), 256, 0, stream>>>(
        oatt, wot + l * 16384, bo + l * 128, xp, g1 + l * 128, b1 + l * 128, x1, 128);
    k_gemm<1, 0, 0, 1><<<dim3(32, 2), 256, 0, stream>>>(
        x1, w1t + l * 32768, bf1 + l * 256, nullptr, nullptr, nullptr, ff1, 256);
    k_gemm<0, 1, 1, 2><<<dim3(32, 1), 256, 0, stream>>>(
        ff1, w2t + l * 32768, bf2 + l * 128, x1, g2 + l * 128, b2 + l * 128, xp, 128);
  }

  k_pool<<<32, 128, 0, stream>>>(xp, (float*)d_out);
}

// Round 6
// 336.770 us; speedup vs baseline: 3.3066x; 1.2812x over previous
//
#include <hip/hip_runtime.h>

// ---------------------------------------------------------------------------
// GraphEncoder: B=32 x N=128, E=128, H=8, DH=16, L=4, M=16384 edges.
// Round 6: launch-count reduction. 33 -> 18 dispatches:
//   k_setup = node_proj + zero(agg) + rbf + all weight prep/transposes
//   k_layerout = Wo+bias+res+LN + FFN1+relu + FFN2+bias+res+LN fused;
//     x1 residual lives in fp32 registers, x1/ff1 live in LDS only.
// tbuild/contract/qkv-gemm/attn unchanged (verified rounds 3/5).
// ---------------------------------------------------------------------------

typedef __attribute__((ext_vector_type(8))) short bf16x8;
typedef __attribute__((ext_vector_type(4))) float f32x4;
#define MFMA16(a, b, c) __builtin_amdgcn_mfma_f32_16x16x32_bf16(a, b, c, 0, 0, 0)

__device__ inline unsigned short f2bf(float f) {          // RTNE
  unsigned u = __float_as_uint(f);
  u = (u + 0x7FFF + ((u >> 16) & 1)) >> 16;
  return (unsigned short)u;
}
__device__ inline unsigned pack2(float a, float b) {
  return (unsigned)f2bf(a) | ((unsigned)f2bf(b) << 16);
}
__device__ inline float bf2f(unsigned short v) {
  return __uint_as_float(((unsigned)v) << 16);
}

// ---------------------------------------------------------------------------
// k_setup: blocks 0..2047 = node_proj (2 nodes/block); blocks 2048..12287 =
// flat elementwise segments (zero agg | rbf | prep_w | qkvt | wot | w1t | w2t)
// ---------------------------------------------------------------------------
__global__ __launch_bounds__(256) void k_setup(
    const float* __restrict__ x, const float* __restrict__ Wproj,
    const float* __restrict__ bproj, float* __restrict__ h,
    unsigned short* __restrict__ hb,
    const float* __restrict__ ea, float* __restrict__ ea2,
    const float* __restrict__ Wlin, const float* __restrict__ blin,
    unsigned short* __restrict__ wb,
    const float* __restrict__ Wq, const float* __restrict__ Wk,
    const float* __restrict__ Wv, const float* __restrict__ bq,
    const float* __restrict__ bk, const float* __restrict__ bv,
    unsigned short* __restrict__ qkvt, float* __restrict__ qkvb,
    const float* __restrict__ Wo, unsigned short* __restrict__ wot,
    const float* __restrict__ W1, unsigned short* __restrict__ w1t,
    const float* __restrict__ W2, unsigned short* __restrict__ w2t,
    float* __restrict__ agg) {
  __shared__ float xs[2][64];
  int blk = blockIdx.x, t = threadIdx.x;
  if (blk < 2048) {                       // ---- node projection ----
    int sub = t >> 7, e = t & 127;
    int n = blk * 2 + sub;
    if (e < 64) xs[sub][e] = x[n * 64 + e];
    __syncthreads();
    float acc = bproj[e];
#pragma unroll
    for (int a = 0; a < 64; a++) acc += xs[sub][a] * Wproj[a * 128 + e];
    h[n * 128 + e] = acc;
    hb[n * 128 + e] = f2bf(acc);
    return;
  }
  int idx = (blk - 2048) * 256 + t;       // 0 .. 2621439
  if (idx < 524288) {                     // ---- zero agg ----
    agg[idx] = 0.0f;
    return;
  }
  idx -= 524288;
  if (idx < 786432) {                     // ---- rbf/ea2 ----
    int m = idx / 48, c = idx % 48;
    float v;
    if (c < 15) {
      v = ea[m * 16 + c];
    } else if (c < 47) {
      int i = c - 15;
      float d = fminf(10.0f, fmaxf(0.0f, ea[m * 16 + 15]));
      float diff = d - 5.0f * (float)i / 31.0f;
      v = __expf(-38.44f * diff * diff);
    } else {
      v = 1.0f;
    }
    ea2[m * 48 + c] = v;
    return;
  }
  idx -= 786432;
  if (idx < 786432) {                     // ---- wb (Wlin+blin bf16) ----
    float v = (idx < 770048) ? Wlin[idx] : blin[idx - 770048];
    wb[idx] = f2bf(v);
    return;
  }
  idx -= 786432;
  if (idx < 196608) {                     // ---- qkvt + qkvb ----
    int l = idx / 49152, r = idx % 49152;
    int j = r / 128, a = r % 128;
    int jj = j & 127;
    const float* W = (j < 128) ? Wq : (j < 256) ? Wk : Wv;
    qkvt[idx] = f2bf(W[l * 16384 + a * 128 + jj]);
    if (a == 0) {
      const float* bb = (j < 128) ? bq : (j < 256) ? bk : bv;
      qkvb[l * 384 + j] = bb[l * 128 + jj];
    }
    return;
  }
  idx -= 196608;
  if (idx < 65536) {                      // ---- wot [l][128out][128k] ----
    int l = idx / 16384, r = idx % 16384;
    int a = r / 128, j = r % 128;
    wot[l * 16384 + j * 128 + a] = f2bf(Wo[idx]);
    return;
  }
  idx -= 65536;
  if (idx < 131072) {                     // ---- w1t [l][256out][128k] ----
    int l = idx / 32768, r = idx % 32768;
    int a = r / 256, j = r % 256;
    w1t[l * 32768 + j * 128 + a] = f2bf(W1[idx]);
    return;
  }
  idx -= 131072;
  {                                       // ---- w2t [l][128out][256k] ----
    int l = idx / 32768, r = idx % 32768;
    int a = r / 128, j = r % 128;
    w2t[l * 32768 + j * 256 + a] = f2bf(W2[idx]);
  }
}

// T[n][c][e] = sum_f hb[n,f] * wb[c][e*128+f]   (verified round 3)
__global__ __launch_bounds__(256) void k_tbuild(const unsigned short* __restrict__ hb,
    const unsigned short* __restrict__ wb, unsigned short* __restrict__ T) {
  __shared__ unsigned short hs[16384];
  __shared__ unsigned short wsm[16384];
  int c = blockIdx.x >> 5;
  int n0 = (blockIdx.x & 31) << 7;
  int t = threadIdx.x;
  const uint4* hg = (const uint4*)hb + n0 * 16;
  const uint4* wg = (const uint4*)wb + c * 2048;
  uint4* hs4 = (uint4*)hs;
  uint4* ws4 = (uint4*)wsm;
#pragma unroll
  for (int i = 0; i < 8; i++) {
    int q = t + i * 256;
    int row = q >> 4, ch = q & 15;
    int d = row * 16 + (ch ^ (row & 7));
    hs4[d] = hg[q];
    ws4[d] = wg[q];
  }
  __syncthreads();
  int w = t >> 6, l = t & 63;
  int lr = l & 15, lg = l >> 4;
  f32x4 acc[2][8];
#pragma unroll
  for (int et = 0; et < 2; et++)
#pragma unroll
    for (int n = 0; n < 8; n++) acc[et][n] = (f32x4){0.f, 0.f, 0.f, 0.f};
#pragma unroll
  for (int s = 0; s < 4; s++) {
    bf16x8 af[2];
#pragma unroll
    for (int et = 0; et < 2; et++) {
      int er = w * 32 + et * 16 + lr;
      int ch = (s * 4 + lg) ^ (er & 7);
      af[et] = *(const bf16x8*)&wsm[(er * 16 + ch) * 8];
    }
#pragma unroll
    for (int n = 0; n < 8; n++) {
      int nr = n * 16 + lr;
      int ch = (s * 4 + lg) ^ (nr & 7);
      bf16x8 bfr = *(const bf16x8*)&hs[(nr * 16 + ch) * 8];
      acc[0][n] = MFMA16(af[0], bfr, acc[0][n]);
      acc[1][n] = MFMA16(af[1], bfr, acc[1][n]);
    }
  }
#pragma unroll
  for (int et = 0; et < 2; et++)
#pragma unroll
    for (int n = 0; n < 8; n++) {
      int node = n0 + n * 16 + lr;
      int e0 = w * 32 + et * 16 + lg * 4;
      uint2 pk;
      pk.x = pack2(acc[et][n][0], acc[et][n][1]);
      pk.y = pack2(acc[et][n][2], acc[et][n][3]);
      *(uint2*)&T[node * 6144 + c * 128 + e0] = pk;
    }
}

// msg[m,e] = sum_c ea2[m,c]*T[src][c][e]; atomicAdd agg[dst,e]
__global__ __launch_bounds__(128) void k_contract(const float* __restrict__ ea2,
    const int* __restrict__ ei, const unsigned short* __restrict__ T,
    float* __restrict__ agg) {
  int m = blockIdx.x, e = threadIdx.x;
  int src = ei[16384 + m], dst = ei[m];
  __shared__ float ec[48];
  if (e < 48) ec[e] = ea2[m * 48 + e];
  __syncthreads();
  const unsigned short* Ts = T + src * 6144;
  float acc = 0.0f;
#pragma unroll 6
  for (int c = 0; c < 48; c++) acc += ec[c] * bf2f(Ts[c * 128 + e]);
  atomicAdd(&agg[dst * 128 + e], acc);
}

// standalone LN (edge-network epilogue only)
__global__ __launch_bounds__(128) void k_ln(const float* __restrict__ in,
    const float* __restrict__ res, const float* __restrict__ g,
    const float* __restrict__ b, float* __restrict__ out) {
  int n = blockIdx.x, e = threadIdx.x;
  float v = in[n * 128 + e];
  if (res) v += res[n * 128 + e];
  float s = v, s2 = v * v;
#pragma unroll
  for (int o = 1; o < 64; o <<= 1) { s += __shfl_xor(s, o); s2 += __shfl_xor(s2, o); }
  __shared__ float r0[2], r1[2];
  int wid = e >> 6;
  if ((e & 63) == 0) { r0[wid] = s; r1[wid] = s2; }
  __syncthreads();
  float ts = r0[0] + r0[1], ts2 = r1[0] + r1[1];
  float mu = ts * (1.0f / 128.0f);
  float var = fmaxf(ts2 * (1.0f / 128.0f) - mu * mu, 0.0f);
  float inv = rsqrtf(var + 1e-5f);
  out[n * 128 + e] = (v - mu) * inv * g[e] + b[e];
}

__global__ __launch_bounds__(128) void k_dist(const float* __restrict__ pos, float* __restrict__ db) {
  int bi = blockIdx.x;
  int b = bi >> 7, i = bi & 127, j = threadIdx.x;
  float x0 = pos[(b * 128 + i) * 3 + 0];
  float y0 = pos[(b * 128 + i) * 3 + 1];
  float z0 = pos[(b * 128 + i) * 3 + 2];
  float dx = x0 - pos[(b * 128 + j) * 3 + 0];
  float dy = y0 - pos[(b * 128 + j) * 3 + 1];
  float dz = z0 - pos[(b * 128 + j) * 3 + 2];
  float d2 = dx * dx + dy * dy + dz * dz;
  db[b * 16384 + i * 128 + j] = (d2 > 0.0f) ? sqrtf(d2) : 0.0f;
}

// Reusable MFMA GEMM (verified round 5) — used for QKV only now.
template <int RELU, int RES, int LN, int KCH>
__global__ __launch_bounds__(256) void k_gemm(
    const float* __restrict__ A, const unsigned short* __restrict__ Bt,
    const float* __restrict__ bias, const float* __restrict__ res,
    const float* __restrict__ g, const float* __restrict__ bb,
    float* __restrict__ out, int ldc) {
  constexpr int K = KCH * 128;
  __shared__ unsigned short As[16384];
  __shared__ unsigned short Bs[16384];
  __shared__ float red[2][4][128];
  int t = threadIdx.x;
  int m0 = blockIdx.x << 7;
  int n0 = blockIdx.y << 7;
  uint4* As4 = (uint4*)As;
  uint4* Bs4 = (uint4*)Bs;
  int w = t >> 6, l = t & 63;
  int lr = l & 15, lg = l >> 4;

  f32x4 acc[2][8];
#pragma unroll
  for (int et = 0; et < 2; et++)
#pragma unroll
    for (int n = 0; n < 8; n++) acc[et][n] = (f32x4){0.f, 0.f, 0.f, 0.f};

  for (int kc = 0; kc < KCH; kc++) {
    if (kc) __syncthreads();
#pragma unroll
    for (int i = 0; i < 8; i++) {
      int q = t + i * 256;
      int row = q >> 4, ch = q & 15;
      int d = row * 16 + (ch ^ (row & 7));
      const float* ap = A + (size_t)(m0 + row) * K + kc * 128 + ch * 8;
      float4 fa = *(const float4*)ap;
      float4 fb = *(const float4*)(ap + 4);
      uint4 pk;
      pk.x = pack2(fa.x, fa.y); pk.y = pack2(fa.z, fa.w);
      pk.z = pack2(fb.x, fb.y); pk.w = pack2(fb.z, fb.w);
      As4[d] = pk;
      Bs4[d] = *((const uint4*)(Bt + (size_t)(n0 + row) * K + kc * 128) + ch);
    }
    __syncthreads();
#pragma unroll
    for (int s = 0; s < 4; s++) {
      bf16x8 af[2];
#pragma unroll
      for (int et = 0; et < 2; et++) {
        int er = w * 32 + et * 16 + lr;
        int ch = (s * 4 + lg) ^ (er & 7);
        af[et] = *(const bf16x8*)&Bs[(er * 16 + ch) * 8];
      }
#pragma unroll
      for (int n = 0; n < 8; n++) {
        int nr = n * 16 + lr;
        int ch = (s * 4 + lg) ^ (nr & 7);
        bf16x8 bfr = *(const bf16x8*)&As[(nr * 16 + ch) * 8];
        acc[0][n] = MFMA16(af[0], bfr, acc[0][n]);
        acc[1][n] = MFMA16(af[1], bfr, acc[1][n]);
      }
    }
  }

  float4 b4[2];
#pragma unroll
  for (int et = 0; et < 2; et++)
    b4[et] = *(const float4*)&bias[n0 + w * 32 + et * 16 + lg * 4];
  float v[2][8][4];
#pragma unroll
  for (int et = 0; et < 2; et++)
#pragma unroll
    for (int n = 0; n < 8; n++) {
      int node = m0 + n * 16 + lr;
      float4 rv;
      if (RES) rv = *(const float4*)&res[(size_t)node * 128 + w * 32 + et * 16 + lg * 4];
#pragma unroll
      for (int r = 0; r < 4; r++) {
        float xv = acc[et][n][r] + ((const float*)&b4[et])[r];
        if (RELU) xv = fmaxf(xv, 0.0f);
        if (RES) xv += ((const float*)&rv)[r];
        v[et][n][r] = xv;
      }
    }

  if (LN) {
    float s[8], s2[8];
#pragma unroll
    for (int n = 0; n < 8; n++) {
      float a = 0, b2s = 0;
#pragma unroll
      for (int et = 0; et < 2; et++)
#pragma unroll
        for (int r = 0; r < 4; r++) { a += v[et][n][r]; b2s += v[et][n][r] * v[et][n][r]; }
      s[n] = a; s2[n] = b2s;
    }
#pragma unroll
    for (int off = 16; off < 64; off <<= 1)
#pragma unroll
      for (int n = 0; n < 8; n++) { s[n] += __shfl_xor(s[n], off); s2[n] += __shfl_xor(s2[n], off); }
    if (l < 16) {
#pragma unroll
      for (int n = 0; n < 8; n++) { red[0][w][n * 16 + lr] = s[n]; red[1][w][n * 16 + lr] = s2[n]; }
    }
    __syncthreads();
    float4 g4[2], bb4[2];
#pragma unroll
    for (int et = 0; et < 2; et++) {
      g4[et]  = *(const float4*)&g[w * 32 + et * 16 + lg * 4];
      bb4[et] = *(const float4*)&bb[w * 32 + et * 16 + lg * 4];
    }
#pragma unroll
    for (int n = 0; n < 8; n++) {
      int nloc = n * 16 + lr;
      float ts  = red[0][0][nloc] + red[0][1][nloc] + red[0][2][nloc] + red[0][3][nloc];
      float ts2 = red[1][0][nloc] + red[1][1][nloc] + red[1][2][nloc] + red[1][3][nloc];
      float mu = ts * (1.0f / 128.0f);
      float var = fmaxf(ts2 * (1.0f / 128.0f) - mu * mu, 0.0f);
      float inv = rsqrtf(var + 1e-5f);
      int node = m0 + nloc;
#pragma unroll
      for (int et = 0; et < 2; et++) {
        float4 ov;
#pragma unroll
        for (int r = 0; r < 4; r++)
          ((float*)&ov)[r] = (v[et][n][r] - mu) * inv * ((const float*)&g4[et])[r] + ((const float*)&bb4[et])[r];
        *(float4*)&out[(size_t)node * ldc + w * 32 + et * 16 + lg * 4] = ov;
      }
    }
  } else {
#pragma unroll
    for (int et = 0; et < 2; et++)
#pragma unroll
      for (int n = 0; n < 8; n++) {
        int node = m0 + n * 16 + lr;
        float4 ov;
#pragma unroll
        for (int r = 0; r < 4; r++) ((float*)&ov)[r] = v[et][n][r];
        *(float4*)&out[(size_t)node * ldc + n0 + w * 32 + et * 16 + lg * 4] = ov;
      }
  }
}

// attention for one (b,h); qkv packed [node][384] = q|k|v (verified round 5)
__global__ __launch_bounds__(128) void k_attn(const float* __restrict__ qkv,
    const float* __restrict__ db, float* __restrict__ oatt) {
  __shared__ float ks[128][16], vs[128][16];
  int bh = blockIdx.x, b = bh >> 3, h = bh & 7;
  int i = threadIdx.x;
  int node = b * 128 + i;
  const float4* kr = (const float4*)(qkv + (size_t)node * 384 + 128 + h * 16);
  const float4* vr = (const float4*)(qkv + (size_t)node * 384 + 256 + h * 16);
#pragma unroll
  for (int d4 = 0; d4 < 4; d4++) {
    *(float4*)&ks[i][d4 * 4] = kr[d4];
    *(float4*)&vs[i][d4 * 4] = vr[d4];
  }
  float qr[16];
  const float4* qp = (const float4*)(qkv + (size_t)node * 384 + h * 16);
#pragma unroll
  for (int d4 = 0; d4 < 4; d4++) *(float4*)&qr[d4 * 4] = qp[d4];
  __syncthreads();
  const float4* dbr = (const float4*)(db + b * 16384 + i * 128);
  float rsum = 0.0f, o[16] = {};
  for (int j4 = 0; j4 < 32; j4++) {
    float4 dv = dbr[j4];
#pragma unroll
    for (int u = 0; u < 4; u++) {
      int j = j4 * 4 + u;
      float s = 0.0f;
#pragma unroll
      for (int d = 0; d < 16; d++) s += qr[d] * ks[j][d];
      s = s * 0.25f + ((const float*)&dv)[u];
      s = fminf(10.0f, fmaxf(-10.0f, s));
      float p = __expf(s);
      rsum += p;
#pragma unroll
      for (int d = 0; d < 16; d++) o[d] += p * vs[j][d];
    }
  }
  float r = 1.0f / rsum;
  float* op = oatt + (size_t)node * 128 + h * 16;
#pragma unroll
  for (int d4 = 0; d4 < 4; d4++)
    *(float4*)&op[d4 * 4] = make_float4(o[d4 * 4] * r, o[d4 * 4 + 1] * r, o[d4 * 4 + 2] * r, o[d4 * 4 + 3] * r);
}

// ---------------------------------------------------------------------------
// k_layerout: fused  x1 = LN(xp + oatt@Wo + bo; g1,b1)
//                    ff = relu(x1@W1 + bf1)
//                    xp' = LN(x1 + ff@W2 + bf2; g2,b2)
// M-tile = 64 nodes, full 128 cols. 256 thr / 4 waves. x1 fp32 in regs;
// x1/ff bf16 in LDS (k_gemm fragment layout + XOR swizzle). In-place xp ok
// (each block reads/writes only its own 64 rows).
// ---------------------------------------------------------------------------
__global__ __launch_bounds__(256) void k_layerout(
    const float* __restrict__ oatt, float* __restrict__ xp,
    const unsigned short* __restrict__ wot, const float* __restrict__ bo,
    const float* __restrict__ g1, const float* __restrict__ b1,
    const unsigned short* __restrict__ w1t, const float* __restrict__ bf1,
    const unsigned short* __restrict__ w2t, const float* __restrict__ bf2,
    const float* __restrict__ g2, const float* __restrict__ b2) {
  __shared__ unsigned short ffs[16384];   // [64][32ch][8] 32KB; ph1: A-stage [64][16ch]
  __shared__ unsigned short x1s[8192];    // [64][16ch][8] 16KB
  __shared__ unsigned short Bs[16384];    // B chunk staging 32KB
  __shared__ float red[2][4][64];
  int t = threadIdx.x;
  int m0 = blockIdx.x << 6;
  int w = t >> 6, l = t & 63, lr = l & 15, lg = l >> 4;

  // ---- phase 1: Wo GEMM ----
  {
    uint4* a4 = (uint4*)ffs;
#pragma unroll
    for (int i = 0; i < 4; i++) {          // A: 64 rows x 16 chunks
      int q = t + i * 256;
      int row = q >> 4, ch = q & 15;
      const float* ap = oatt + (size_t)(m0 + row) * 128 + ch * 8;
      float4 fa = *(const float4*)ap;
      float4 fb = *(const float4*)(ap + 4);
      uint4 pk;
      pk.x = pack2(fa.x, fa.y); pk.y = pack2(fa.z, fa.w);
      pk.z = pack2(fb.x, fb.y); pk.w = pack2(fb.z, fb.w);
      a4[row * 16 + (ch ^ (row & 7))] = pk;
    }
    uint4* b4p = (uint4*)Bs;
#pragma unroll
    for (int i = 0; i < 8; i++) {          // B: 128 rows x 16 chunks
      int q = t + i * 256;
      int row = q >> 4, ch = q & 15;
      b4p[row * 16 + (ch ^ (row & 7))] = *((const uint4*)(wot + (size_t)row * 128) + ch);
    }
  }
  __syncthreads();
  f32x4 acc[2][4];
#pragma unroll
  for (int et = 0; et < 2; et++)
#pragma unroll
    for (int n = 0; n < 4; n++) acc[et][n] = (f32x4){0.f, 0.f, 0.f, 0.f};
#pragma unroll
  for (int s = 0; s < 4; s++) {
    bf16x8 af[2];
#pragma unroll
    for (int et = 0; et < 2; et++) {
      int er = w * 32 + et * 16 + lr;
      int ch = (s * 4 + lg) ^ (er & 7);
      af[et] = *(const bf16x8*)&Bs[(er * 16 + ch) * 8];
    }
#pragma unroll
    for (int n = 0; n < 4; n++) {
      int nr = n * 16 + lr;
      int ch = (s * 4 + lg) ^ (nr & 7);
      bf16x8 bfr = *(const bf16x8*)&ffs[(nr * 16 + ch) * 8];
      acc[0][n] = MFMA16(af[0], bfr, acc[0][n]);
      acc[1][n] = MFMA16(af[1], bfr, acc[1][n]);
    }
  }
  // epilogue 1: + bo + xp residual -> LN(g1,b1) -> v1 regs + x1s bf16
  float v1[2][4][4];
  {
    int e0 = w * 32 + lg * 4;
    float4 bo4[2] = { *(const float4*)&bo[e0], *(const float4*)&bo[e0 + 16] };
#pragma unroll
    for (int et = 0; et < 2; et++)
#pragma unroll
      for (int n = 0; n < 4; n++) {
        int node = m0 + n * 16 + lr;
        float4 rv = *(const float4*)&xp[(size_t)node * 128 + e0 + et * 16];
#pragma unroll
        for (int r = 0; r < 4; r++)
          v1[et][n][r] = acc[et][n][r] + ((const float*)&bo4[et])[r] + ((const float*)&rv)[r];
      }
    float s[4], s2[4];
#pragma unroll
    for (int n = 0; n < 4; n++) {
      float a = 0, b2s = 0;
#pragma unroll
      for (int et = 0; et < 2; et++)
#pragma unroll
        for (int r = 0; r < 4; r++) { a += v1[et][n][r]; b2s += v1[et][n][r] * v1[et][n][r]; }
      s[n] = a; s2[n] = b2s;
    }
#pragma unroll
    for (int off = 16; off < 64; off <<= 1)
#pragma unroll
      for (int n = 0; n < 4; n++) { s[n] += __shfl_xor(s[n], off); s2[n] += __shfl_xor(s2[n], off); }
    if (l < 16) {
#pragma unroll
      for (int n = 0; n < 4; n++) { red[0][w][n * 16 + lr] = s[n]; red[1][w][n * 16 + lr] = s2[n]; }
    }
    __syncthreads();
    float4 g4[2] = { *(const float4*)&g1[e0], *(const float4*)&g1[e0 + 16] };
    float4 bb4[2] = { *(const float4*)&b1[e0], *(const float4*)&b1[e0 + 16] };
#pragma unroll
    for (int n = 0; n < 4; n++) {
      int nloc = n * 16 + lr;
      float ts  = red[0][0][nloc] + red[0][1][nloc] + red[0][2][nloc] + red[0][3][nloc];
      float ts2 = red[1][0][nloc] + red[1][1][nloc] + red[1][2][nloc] + red[1][3][nloc];
      float mu = ts * (1.0f / 128.0f);
      float var = fmaxf(ts2 * (1.0f / 128.0f) - mu * mu, 0.0f);
      float inv = rsqrtf(var + 1e-5f);
#pragma unroll
      for (int et = 0; et < 2; et++) {
#pragma unroll
        for (int r = 0; r < 4; r++)
          v1[et][n][r] = (v1[et][n][r] - mu) * inv * ((const float*)&g4[et])[r] + ((const float*)&bb4[et])[r];
        int ch = w * 4 + et * 2 + (lg >> 1);
        uint2 pk;
        pk.x = pack2(v1[et][n][0], v1[et][n][1]);
        pk.y = pack2(v1[et][n][2], v1[et][n][3]);
        *(uint2*)&x1s[(nloc * 16 + (ch ^ (nloc & 7))) * 8 + (lg & 1) * 4] = pk;
      }
    }
  }
  __syncthreads();   // x1s ready; phase-1 Bs/ffs reads done

  // ---- phase 2: FFN1 (two 128-col tiles), relu, ff -> ffs [64][32ch] ----
  for (int ct = 0; ct < 2; ct++) {
    if (ct) __syncthreads();               // Bs reads of ct=0 done
    uint4* b4p = (uint4*)Bs;
#pragma unroll
    for (int i = 0; i < 8; i++) {
      int q = t + i * 256;
      int row = q >> 4, ch = q & 15;
      b4p[row * 16 + (ch ^ (row & 7))] =
          *((const uint4*)(w1t + (size_t)(ct * 128 + row) * 128) + ch);
    }
    __syncthreads();
#pragma unroll
    for (int et = 0; et < 2; et++)
#pragma unroll
      for (int n = 0; n < 4; n++) acc[et][n] = (f32x4){0.f, 0.f, 0.f, 0.f};
#pragma unroll
    for (int s = 0; s < 4; s++) {
      bf16x8 af[2];
#pragma unroll
      for (int et = 0; et < 2; et++) {
        int er = w * 32 + et * 16 + lr;
        int ch = (s * 4 + lg) ^ (er & 7);
        af[et] = *(const bf16x8*)&Bs[(er * 16 + ch) * 8];
      }
#pragma unroll
      for (int n = 0; n < 4; n++) {
        int nr = n * 16 + lr;
        int ch = (s * 4 + lg) ^ (nr & 7);
        bf16x8 bfr = *(const bf16x8*)&x1s[(nr * 16 + ch) * 8];
        acc[0][n] = MFMA16(af[0], bfr, acc[0][n]);
        acc[1][n] = MFMA16(af[1], bfr, acc[1][n]);
      }
    }
    int e0 = w * 32 + lg * 4;
    float4 bb0 = *(const float4*)&bf1[ct * 128 + e0];
    float4 bb1 = *(const float4*)&bf1[ct * 128 + e0 + 16];
#pragma unroll
    for (int et = 0; et < 2; et++) {
      const float* bbp = et ? (const float*)&bb1 : (const float*)&bb0;
#pragma unroll
      for (int n = 0; n < 4; n++) {
        int nloc = n * 16 + lr;
        float f0 = fmaxf(acc[et][n][0] + bbp[0], 0.0f);
        float f1 = fmaxf(acc[et][n][1] + bbp[1], 0.0f);
        float f2 = fmaxf(acc[et][n][2] + bbp[2], 0.0f);
        float f3 = fmaxf(acc[et][n][3] + bbp[3], 0.0f);
        int cg = ct * 16 + w * 4 + et * 2 + (lg >> 1);
        uint2 pk;
        pk.x = pack2(f0, f1);
        pk.y = pack2(f2, f3);
        *(uint2*)&ffs[(nloc * 32 + (cg ^ (nloc & 7))) * 8 + (lg & 1) * 4] = pk;
      }
    }
  }
  __syncthreads();   // ffs complete

  // ---- phase 3: FFN2 (K=256, 2 k-chunks) + bf2 + x1 res + LN(g2,b2) ----
  f32x4 acc3[2][4];
#pragma unroll
  for (int et = 0; et < 2; et++)
#pragma unroll
    for (int n = 0; n < 4; n++) acc3[et][n] = (f32x4){0.f, 0.f, 0.f, 0.f};
  for (int kc = 0; kc < 2; kc++) {
    if (kc) __syncthreads();
    uint4* b4p = (uint4*)Bs;
#pragma unroll
    for (int i = 0; i < 8; i++) {
      int q = t + i * 256;
      int row = q >> 4, ch = q & 15;
      b4p[row * 16 + (ch ^ (row & 7))] =
          *((const uint4*)(w2t + (size_t)row * 256 + kc * 128) + ch);
    }
    __syncthreads();
#pragma unroll
    for (int s = 0; s < 4; s++) {
      bf16x8 af[2];
#pragma unroll
      for (int et = 0; et < 2; et++) {
        int er = w * 32 + et * 16 + lr;
        int ch = (s * 4 + lg) ^ (er & 7);
        af[et] = *(const bf16x8*)&Bs[(er * 16 + ch) * 8];
      }
#pragma unroll
      for (int n = 0; n < 4; n++) {
        int nr = n * 16 + lr;
        int gch = kc * 16 + s * 4 + lg;
        bf16x8 bfr = *(const bf16x8*)&ffs[(nr * 32 + (gch ^ (nr & 7))) * 8];
        acc3[0][n] = MFMA16(af[0], bfr, acc3[0][n]);
        acc3[1][n] = MFMA16(af[1], bfr, acc3[1][n]);
      }
    }
  }
  {
    int e0 = w * 32 + lg * 4;
    float4 bo4[2] = { *(const float4*)&bf2[e0], *(const float4*)&bf2[e0 + 16] };
    float v2[2][4][4];
#pragma unroll
    for (int et = 0; et < 2; et++)
#pragma unroll
      for (int n = 0; n < 4; n++)
#pragma unroll
        for (int r = 0; r < 4; r++)
          v2[et][n][r] = acc3[et][n][r] + ((const float*)&bo4[et])[r] + v1[et][n][r];
    float s[4], s2[4];
#pragma unroll
    for (int n = 0; n < 4; n++) {
      float a = 0, b2s = 0;
#pragma unroll
      for (int et = 0; et < 2; et++)
#pragma unroll
        for (int r = 0; r < 4; r++) { a += v2[et][n][r]; b2s += v2[et][n][r] * v2[et][n][r]; }
      s[n] = a; s2[n] = b2s;
    }
#pragma unroll
    for (int off = 16; off < 64; off <<= 1)
#pragma unroll
      for (int n = 0; n < 4; n++) { s[n] += __shfl_xor(s[n], off); s2[n] += __shfl_xor(s2[n], off); }
    __syncthreads();                        // red reuse safe
    if (l < 16) {
#pragma unroll
      for (int n = 0; n < 4; n++) { red[0][w][n * 16 + lr] = s[n]; red[1][w][n * 16 + lr] = s2[n]; }
    }
    __syncthreads();
    float4 g4[2] = { *(const float4*)&g2[e0], *(const float4*)&g2[e0 + 16] };
    float4 bb4[2] = { *(const float4*)&b2[e0], *(const float4*)&b2[e0 + 16] };
#pragma unroll
    for (int n = 0; n < 4; n++) {
      int nloc = n * 16 + lr;
      float ts  = red[0][0][nloc] + red[0][1][nloc] + red[0][2][nloc] + red[0][3][nloc];
      float ts2 = red[1][0][nloc] + red[1][1][nloc] + red[1][2][nloc] + red[1][3][nloc];
      float mu = ts * (1.0f / 128.0f);
      float var = fmaxf(ts2 * (1.0f / 128.0f) - mu * mu, 0.0f);
      float inv = rsqrtf(var + 1e-5f);
      int node = m0 + nloc;
#pragma unroll
      for (int et = 0; et < 2; et++) {
        float4 ov;
#pragma unroll
        for (int r = 0; r < 4; r++)
          ((float*)&ov)[r] = (v2[et][n][r] - mu) * inv * ((const float*)&g4[et])[r] + ((const float*)&bb4[et])[r];
        *(float4*)&xp[(size_t)node * 128 + e0 + et * 16] = ov;
      }
    }
  }
}

__global__ __launch_bounds__(128) void k_pool(const float* __restrict__ xp, float* __restrict__ out) {
  int b = blockIdx.x, e = threadIdx.x;
  float s = 0.0f;
  for (int n = 0; n < 128; n++) s += xp[(b * 128 + n) * 128 + e];
  out[b * 128 + e] = s * (1.0f / 128.0f);
}

extern "C" void kernel_launch(void* const* d_in, const int* in_sizes, int n_in,
                              void* d_out, int out_size, void* d_ws, size_t ws_size,
                              hipStream_t stream) {
  const float* x     = (const float*)d_in[0];
  const int*   ei    = (const int*)  d_in[1];
  const float* ea    = (const float*)d_in[2];
  const float* pos   = (const float*)d_in[3];
  const float* Wproj = (const float*)d_in[5];
  const float* bproj = (const float*)d_in[6];
  const float* Wlin  = (const float*)d_in[7];
  const float* blin  = (const float*)d_in[8];
  const float* g_en  = (const float*)d_in[9];
  const float* b_en  = (const float*)d_in[10];
  const float* Wq    = (const float*)d_in[11];
  const float* Wk    = (const float*)d_in[12];
  const float* Wv    = (const float*)d_in[13];
  const float* Wo    = (const float*)d_in[14];
  const float* bq    = (const float*)d_in[15];
  const float* bk    = (const float*)d_in[16];
  const float* bv    = (const float*)d_in[17];
  const float* bo    = (const float*)d_in[18];
  const float* g1    = (const float*)d_in[19];
  const float* b1    = (const float*)d_in[20];
  const float* W1    = (const float*)d_in[21];
  const float* bf1   = (const float*)d_in[22];
  const float* W2    = (const float*)d_in[23];
  const float* bf2   = (const float*)d_in[24];
  const float* g2    = (const float*)d_in[25];
  const float* b2    = (const float*)d_in[26];

  float* ws = (float*)d_ws;
  // region A (persistent): same layout as round 5
  float* ea2  = ws;                                         // 786432
  float* hbuf = ea2  + 786432;                              // 524288
  float* agg  = hbuf + 524288;                              // 524288
  unsigned short* hbf  = (unsigned short*)(agg + 524288);   // 524288 us
  unsigned short* wbf  = hbf + 524288;                      // 786432 us
  unsigned short* qkvt = wbf + 786432;                      // 196608 us
  unsigned short* wot  = qkvt + 196608;                     // 65536 us
  unsigned short* w1t  = wot + 65536;                       // 131072 us
  unsigned short* w2t  = w1t + 131072;                      // 131072 us
  float* qkvb = (float*)(w2t + 131072);                     // 1536 f
  // region B: T [4096][48][128] bf16 = 48 MB
  float* base2 = qkvb + 1536;
  unsigned short* Tb = (unsigned short*)base2;
  // region C aliases T (first write after T dead)
  float* db   = base2;                 // 524288
  float* xp   = db   + 524288;         // 524288
  float* qkv  = xp   + 524288;         // 1572864  [4096][384]
  float* oatt = qkv  + 1572864;        // 524288

  k_setup<<<12288, 256, 0, stream>>>(x, Wproj, bproj, hbuf, hbf,
      ea, ea2, Wlin, blin, wbf, Wq, Wk, Wv, bq, bk, bv, qkvt, qkvb,
      Wo, wot, W1, w1t, W2, w2t, agg);
  k_tbuild<<<1536, 256, 0, stream>>>(hbf, wbf, Tb);
  k_contract<<<16384, 128, 0, stream>>>(ea2, ei, Tb, agg);
  k_ln<<<4096, 128, 0, stream>>>(agg, hbuf, g_en, b_en, xp);  // T dead after
  k_dist<<<4096, 128, 0, stream>>>(pos, db);

  for (int l = 0; l < 4; l++) {
    k_gemm<0, 0, 0, 1><<<dim3(32, 3), 256, 0, stream>>>(
        xp, qkvt + l * 49152, qkvb + l * 384, nullptr, nullptr, nullptr, qkv, 384);
    k_attn<<<256, 128, 0, stream>>>(qkv, db, oatt);
    k_layerout<<<64, 256, 0, stream>>>(oatt, xp,
        wot + l * 16384, bo + l * 128, g1 + l * 128, b1 + l * 128,
        w1t + l * 32768, bf1 + l * 256,
        w2t + l * 32768, bf2 + l * 128, g2 + l * 128, b2 + l * 128);
  }

  k_pool<<<32, 128, 0, stream>>>(xp, (float*)d_out);
}